// Round 1
// baseline (958.907 us; speedup 1.0000x reference)
//
#include <hip/hip_runtime.h>

// GraphSAGE 2-layer + classifier on MI355X.
// Pipeline (transform-before-aggregate, CSR gather aggregation):
//   CSR build: cnt -> scan -> rowptr/cursor -> fill col[]
//   t1 = x @ W1_l.T                      [N,128]  (k_gemm<128,false>)
//   agg1[n] = sum_{j in nbrs(n)} t1[j]   [N,128]  (k_agg<128>)
//   h1 = relu(agg1/deg + x @ W1_r.T + b1)         (k_gemm<128,true>, out aliases t1)
//   y2 = h1 @ W2_l.T                     [N,64]   (k_gemm<64,false>)
//   agg2[n] = sum y2[nbrs]               [N,64]   (k_agg<64>)
//   h2 = relu(agg2/deg + h1 @ W2_r.T + b2)        (k_gemm<64,true>, out aliases y2)
//   logits = h2 @ Wc.T + bc              [N,1]    (k_cls)

static constexpr int TPB = 256;

__global__ void k_zero(int* __restrict__ p, int n) {
  int i = blockIdx.x * blockDim.x + threadIdx.x;
  if (i < n) p[i] = 0;
}

__global__ void k_count(const int* __restrict__ dst, int* __restrict__ cnt, int E) {
  int i = blockIdx.x * blockDim.x + threadIdx.x;
  if (i < E) atomicAdd(&cnt[dst[i]], 1);
}

// --- exclusive scan over cnt[N] -> rowptr, cursor (3-kernel, chunk=1024) ---
__global__ void k_scan_a(const int* __restrict__ cnt, int* __restrict__ bsums, int n) {
  __shared__ int s[TPB];
  int t = threadIdx.x;
  int base = blockIdx.x * 1024 + t * 4;
  int v = 0;
#pragma unroll
  for (int j = 0; j < 4; ++j) { int idx = base + j; if (idx < n) v += cnt[idx]; }
  s[t] = v; __syncthreads();
  for (int off = TPB / 2; off > 0; off >>= 1) {
    if (t < off) s[t] += s[t + off];
    __syncthreads();
  }
  if (t == 0) bsums[blockIdx.x] = s[0];
}

__global__ void k_scan_b(int* __restrict__ bsums, int nb) {
  __shared__ int s[128];
  int t = threadIdx.x;
  int v = (t < nb) ? bsums[t] : 0;
  s[t] = v; __syncthreads();
  for (int off = 1; off < 128; off <<= 1) {
    int x = (t >= off) ? s[t - off] : 0;
    __syncthreads();
    s[t] += x;
    __syncthreads();
  }
  if (t < nb) bsums[t] = s[t] - v;  // exclusive
}

__global__ void k_scan_c(const int* __restrict__ cnt, const int* __restrict__ bsums,
                         int* __restrict__ rowptr, int* __restrict__ cursor,
                         int n, int total) {
  __shared__ int s[TPB];
  int t = threadIdx.x;
  int base = blockIdx.x * 1024 + t * 4;
  int loc[4]; int v = 0;
#pragma unroll
  for (int j = 0; j < 4; ++j) { int idx = base + j; loc[j] = (idx < n) ? cnt[idx] : 0; v += loc[j]; }
  s[t] = v; __syncthreads();
  for (int off = 1; off < TPB; off <<= 1) {
    int x = (t >= off) ? s[t - off] : 0;
    __syncthreads();
    s[t] += x;
    __syncthreads();
  }
  int run = bsums[blockIdx.x] + (s[t] - v);
#pragma unroll
  for (int j = 0; j < 4; ++j) {
    int idx = base + j;
    if (idx < n) { rowptr[idx] = run; cursor[idx] = run; run += loc[j]; }
  }
  if (blockIdx.x == 0 && t == 0) rowptr[n] = total;
}

__global__ void k_fill(const int* __restrict__ src, const int* __restrict__ dst,
                       int* __restrict__ cursor, int* __restrict__ col, int E) {
  int i = blockIdx.x * blockDim.x + threadIdx.x;
  if (i < E) {
    int p = atomicAdd(&cursor[dst[i]], 1);
    col[p] = src[i];
  }
}

// out[r][c] = X[r]·W[c](len 128), optionally + agg[r][c]/max(deg,1) + bias[c], relu.
// W staged k-major in LDS (conflict-free: bank = cg), 32 rows/iter staged in LDS.
// Each thread: 4 rows x (DOUT/32) cols. Requires n % 32 == 0 (100000 = 32*3125).
template <int DOUT, bool FUSE>
__global__ __launch_bounds__(TPB) void k_gemm(
    const float* __restrict__ X, const float* __restrict__ W,
    const float* __restrict__ bias, const float* __restrict__ agg,
    const int* __restrict__ cnt, float* __restrict__ out, int ntiles) {
  __shared__ float Wt[128 * DOUT];
  __shared__ float xs[32 * 128];
  int t = threadIdx.x;
  for (int i = t; i < 128 * DOUT; i += TPB) {
    int c = i >> 7, k = i & 127;
    Wt[k * DOUT + c] = W[i];
  }
  int cg = t & 31, rq = t >> 5;
  constexpr int J = DOUT / 32;
  for (int tile = blockIdx.x; tile < ntiles; tile += gridDim.x) {
    int row0 = tile * 32;
    __syncthreads();
    for (int ii = t * 4; ii < 32 * 128; ii += TPB * 4)
      *(float4*)&xs[ii] = *(const float4*)&X[(size_t)row0 * 128 + ii];
    __syncthreads();
    float acc[4][J];
#pragma unroll
    for (int i = 0; i < 4; ++i)
#pragma unroll
      for (int j = 0; j < J; ++j) acc[i][j] = 0.f;
#pragma unroll 4
    for (int k = 0; k < 128; ++k) {
      float w[J];
#pragma unroll
      for (int j = 0; j < J; ++j) w[j] = Wt[k * DOUT + cg + 32 * j];
#pragma unroll
      for (int i = 0; i < 4; ++i) {
        float xv = xs[(rq * 4 + i) * 128 + k];
#pragma unroll
        for (int j = 0; j < J; ++j) acc[i][j] += xv * w[j];
      }
    }
#pragma unroll
    for (int i = 0; i < 4; ++i) {
      int r = row0 + rq * 4 + i;
      float inv = 1.f;
      if (FUSE) { int d = cnt[r]; inv = 1.f / (float)(d > 1 ? d : 1); }
#pragma unroll
      for (int j = 0; j < J; ++j) {
        int c = cg + 32 * j;
        float v = acc[i][j];
        if (FUSE) {
          v = v + agg[(size_t)r * DOUT + c] * inv + bias[c];
          v = v > 0.f ? v : 0.f;
        }
        out[(size_t)r * DOUT + c] = v;
      }
    }
  }
}

// one wave per node: sum feat[col[j]] over neighbor list
template <int D>
__global__ void k_agg(const float* __restrict__ feat, const int* __restrict__ rowptr,
                      const int* __restrict__ col, float* __restrict__ out, int n) {
  int wid = (int)(((size_t)blockIdx.x * blockDim.x + threadIdx.x) >> 6);
  int lane = threadIdx.x & 63;
  if (wid >= n) return;
  int rp0 = rowptr[wid], rp1 = rowptr[wid + 1];
  if (D == 128) {
    float ax = 0.f, ay = 0.f;
    for (int j = rp0; j < rp1; ++j) {
      int c = col[j];
      float2 v = *(const float2*)&feat[(size_t)c * 128 + lane * 2];
      ax += v.x; ay += v.y;
    }
    float2 r; r.x = ax; r.y = ay;
    *(float2*)&out[(size_t)wid * 128 + lane * 2] = r;
  } else {
    float a = 0.f;
    for (int j = rp0; j < rp1; ++j) a += feat[(size_t)col[j] * 64 + lane];
    out[(size_t)wid * 64 + lane] = a;
  }
}

__global__ void k_cls(const float* __restrict__ h2, const float* __restrict__ Wc,
                      const float* __restrict__ bc, float* __restrict__ out, int n) {
  int wid = (int)(((size_t)blockIdx.x * blockDim.x + threadIdx.x) >> 6);
  int lane = threadIdx.x & 63;
  if (wid >= n) return;
  float v = h2[(size_t)wid * 64 + lane] * Wc[lane];
  for (int off = 32; off > 0; off >>= 1) v += __shfl_down(v, off, 64);
  if (lane == 0) out[wid] = v + bc[0];
}

extern "C" void kernel_launch(void* const* d_in, const int* in_sizes, int n_in,
                              void* d_out, int out_size, void* d_ws, size_t ws_size,
                              hipStream_t stream) {
  const float* x   = (const float*)d_in[0];
  const int*   ei  = (const int*)d_in[1];
  const float* W1l = (const float*)d_in[2];
  const float* W1r = (const float*)d_in[3];
  const float* b1  = (const float*)d_in[4];
  const float* W2l = (const float*)d_in[5];
  const float* W2r = (const float*)d_in[6];
  const float* b2  = (const float*)d_in[7];
  const float* Wc  = (const float*)d_in[8];
  const float* bc  = (const float*)d_in[9];
  float* logits = (float*)d_out;

  const int N = in_sizes[0] / 128;  // 100000
  const int E = in_sizes[1] / 2;    // 1600000

  char* ws = (char*)d_ws;
  size_t o = 0;
  auto alloc = [&](size_t bytes) { size_t r = o; o += (bytes + 511) & ~511ULL; return r; };
  size_t o_cnt  = alloc((size_t)N * 4);
  size_t o_rp   = alloc((size_t)(N + 1) * 4);
  size_t o_cur  = alloc((size_t)N * 4);
  size_t o_bs   = alloc(512 * 4);
  size_t o_col  = alloc((size_t)E * 4);
  size_t o_t1   = alloc((size_t)N * 128 * 4);
  size_t o_agg1 = alloc((size_t)N * 128 * 4);
  if (o > ws_size) return;  // workspace too small; fail loudly in validation

  int* cnt = (int*)(ws + o_cnt);
  int* rp  = (int*)(ws + o_rp);
  int* cur = (int*)(ws + o_cur);
  int* bs  = (int*)(ws + o_bs);
  int* col = (int*)(ws + o_col);
  float* t1   = (float*)(ws + o_t1);
  float* agg1 = (float*)(ws + o_agg1);
  float* h1   = t1;                       // overwrite t1 after agg1
  float* y2   = agg1;                     // overwrite agg1 after h1
  float* agg2 = agg1 + (size_t)N * 64;    // second half of agg1 slot
  float* h2   = y2;                       // overwrite y2 after agg2

  const int* esrc = ei;
  const int* edst = ei + E;

  // CSR build
  k_zero<<<(N + TPB - 1) / TPB, TPB, 0, stream>>>(cnt, N);
  int eb = (E + TPB - 1) / TPB;
  k_count<<<eb, TPB, 0, stream>>>(edst, cnt, E);
  int nb = (N + 1023) / 1024;  // 98 <= 128
  k_scan_a<<<nb, TPB, 0, stream>>>(cnt, bs, N);
  k_scan_b<<<1, 128, 0, stream>>>(bs, nb);
  k_scan_c<<<nb, TPB, 0, stream>>>(cnt, bs, rp, cur, N, E);
  k_fill<<<eb, TPB, 0, stream>>>(esrc, edst, cur, col, E);

  int ntiles = N / 32;  // 3125, exact
  int ab = (int)(((size_t)N * 64 + TPB - 1) / TPB);  // one wave per node

  // layer 1
  k_gemm<128, false><<<ntiles, TPB, 0, stream>>>(x, W1l, nullptr, nullptr, nullptr, t1, ntiles);
  k_agg<128><<<ab, TPB, 0, stream>>>(t1, rp, col, agg1, N);
  k_gemm<128, true><<<ntiles, TPB, 0, stream>>>(x, W1r, b1, agg1, cnt, h1, ntiles);
  // layer 2
  k_gemm<64, false><<<ntiles, TPB, 0, stream>>>(h1, W2l, nullptr, nullptr, nullptr, y2, ntiles);
  k_agg<64><<<ab, TPB, 0, stream>>>(y2, rp, col, agg2, N);
  k_gemm<64, true><<<ntiles, TPB, 0, stream>>>(h1, W2r, b2, agg2, cnt, h2, ntiles);
  // classifier
  k_cls<<<ab, TPB, 0, stream>>>(h2, Wc, bc, logits, N);
}

// Round 2
// 479.891 us; speedup vs baseline: 1.9982x; 1.9982x over previous
//
#include <hip/hip_runtime.h>

// GraphSAGE 2-layer + classifier on MI355X (gfx950), bf16-MFMA restructure.
//
// Pipeline (transform-before-aggregate, CSR gather, bf16 gather tables):
//   CSR: cnt -> scan -> rowptr/cursor -> fill col[]
//   t1 = bf16(x @ W1l.T)                    k_lin1(W1l)
//   r1 = bf16(x @ W1r.T)                    k_lin1(W1r)
//   agg1 = gather-sum(t1) f32               k_aggb1
//   h1 = relu(agg1/deg + r1 + b1) [LDS only]
//   y2 = bf16(h1 @ W2l.T), r2 = bf16(h1 @ W2r.T)   k_lin2 (fused)
//   agg2 = gather-sum(y2) f32               k_aggb2
//   logits = (relu(agg2/deg + r2 + b2)) . Wc + bc  k_head (fused)

static constexpr int TPB = 256;

typedef __attribute__((ext_vector_type(8))) short bf16x8;
typedef __attribute__((ext_vector_type(4))) float f32x4;

__device__ __forceinline__ unsigned short f2bf(float f) {
  union { float f; unsigned u; } v; v.f = f;
  unsigned r = v.u + 0x7FFFu + ((v.u >> 16) & 1u);  // RNE
  return (unsigned short)(r >> 16);
}
__device__ __forceinline__ float bf2f(unsigned short h) {
  union { unsigned u; float f; } v; v.u = ((unsigned)h) << 16;
  return v.f;
}

// ---------------- CSR build ----------------
__global__ void k_zero(int* __restrict__ p, int n) {
  int i = blockIdx.x * blockDim.x + threadIdx.x;
  if (i < n) p[i] = 0;
}

__global__ void k_count(const int* __restrict__ dst, int* __restrict__ cnt, int E) {
  int i = blockIdx.x * blockDim.x + threadIdx.x;
  if (i < E) atomicAdd(&cnt[dst[i]], 1);
}

__global__ void k_scan_a(const int* __restrict__ cnt, int* __restrict__ bsums, int n) {
  __shared__ int s[TPB];
  int t = threadIdx.x;
  int base = blockIdx.x * 1024 + t * 4;
  int v = 0;
#pragma unroll
  for (int j = 0; j < 4; ++j) { int idx = base + j; if (idx < n) v += cnt[idx]; }
  s[t] = v; __syncthreads();
  for (int off = TPB / 2; off > 0; off >>= 1) {
    if (t < off) s[t] += s[t + off];
    __syncthreads();
  }
  if (t == 0) bsums[blockIdx.x] = s[0];
}

__global__ void k_scan_b(int* __restrict__ bsums, int nb) {
  __shared__ int s[128];
  int t = threadIdx.x;
  int v = (t < nb) ? bsums[t] : 0;
  s[t] = v; __syncthreads();
  for (int off = 1; off < 128; off <<= 1) {
    int x = (t >= off) ? s[t - off] : 0;
    __syncthreads();
    s[t] += x;
    __syncthreads();
  }
  if (t < nb) bsums[t] = s[t] - v;  // exclusive
}

__global__ void k_scan_c(const int* __restrict__ cnt, const int* __restrict__ bsums,
                         int* __restrict__ rowptr, int* __restrict__ cursor,
                         int n, int total) {
  __shared__ int s[TPB];
  int t = threadIdx.x;
  int base = blockIdx.x * 1024 + t * 4;
  int loc[4]; int v = 0;
#pragma unroll
  for (int j = 0; j < 4; ++j) { int idx = base + j; loc[j] = (idx < n) ? cnt[idx] : 0; v += loc[j]; }
  s[t] = v; __syncthreads();
  for (int off = 1; off < TPB; off <<= 1) {
    int x = (t >= off) ? s[t - off] : 0;
    __syncthreads();
    s[t] += x;
    __syncthreads();
  }
  int run = bsums[blockIdx.x] + (s[t] - v);
#pragma unroll
  for (int j = 0; j < 4; ++j) {
    int idx = base + j;
    if (idx < n) { rowptr[idx] = run; cursor[idx] = run; run += loc[j]; }
  }
  if (blockIdx.x == 0 && t == 0) rowptr[n] = total;
}

__global__ void k_fill(const int* __restrict__ src, const int* __restrict__ dst,
                       int* __restrict__ cursor, int* __restrict__ col, int E) {
  int i = blockIdx.x * blockDim.x + threadIdx.x;
  if (i < E) {
    int p = atomicAdd(&cursor[dst[i]], 1);
    col[p] = src[i];
  }
}

// ---------------- bf16 MFMA GEMM: out[r][c] = X[r]·W[c], K=128 ----------------
// BM=64 rows/block, NOUT=128 cols, 4 waves (wave w -> cols [w*32, w*32+32)).
// LDS padded to LD=136 bf16/row -> 2-way bank aliasing only (free).
static constexpr int LD = 136;

__global__ __launch_bounds__(TPB) void k_lin1(
    const float* __restrict__ X, const float* __restrict__ W,
    unsigned short* __restrict__ out, int N) {
  __shared__ unsigned short Bs[128 * LD];
  __shared__ unsigned short As[64 * LD];
  int t = threadIdx.x;
  for (int i = t; i < 128 * 32; i += TPB) {  // stage B (W row-major [c][k])
    int r = i >> 5, k4 = i & 31;
    float4 v = *(const float4*)&W[r * 128 + k4 * 4];
    ushort4 o; o.x = f2bf(v.x); o.y = f2bf(v.y); o.z = f2bf(v.z); o.w = f2bf(v.w);
    *(ushort4*)&Bs[r * LD + k4 * 4] = o;
  }
  int row0 = blockIdx.x * 64;
  for (int i = t; i < 64 * 32; i += TPB) {  // stage A (x rows)
    int r = i >> 5, k4 = i & 31;
    int gr = row0 + r;
    float4 v;
    if (gr < N) v = *(const float4*)&X[(size_t)gr * 128 + k4 * 4];
    else { v.x = v.y = v.z = v.w = 0.f; }
    ushort4 o; o.x = f2bf(v.x); o.y = f2bf(v.y); o.z = f2bf(v.z); o.w = f2bf(v.w);
    *(ushort4*)&As[r * LD + k4 * 4] = o;
  }
  __syncthreads();
  int w = t >> 6, l = t & 63;
  int lr = l & 15, lk = l >> 4;  // lr: row/col-in-frag, lk: k-group
  f32x4 acc[4][2];
#pragma unroll
  for (int mb = 0; mb < 4; ++mb)
#pragma unroll
    for (int nb = 0; nb < 2; ++nb)
#pragma unroll
      for (int q = 0; q < 4; ++q) acc[mb][nb][q] = 0.f;
#pragma unroll
  for (int ks = 0; ks < 4; ++ks) {
    int koff = ks * 32 + lk * 8;
    bf16x8 a[4], b[2];
#pragma unroll
    for (int mb = 0; mb < 4; ++mb)
      a[mb] = *(const bf16x8*)&As[(mb * 16 + lr) * LD + koff];
#pragma unroll
    for (int nb = 0; nb < 2; ++nb)
      b[nb] = *(const bf16x8*)&Bs[(w * 32 + nb * 16 + lr) * LD + koff];
#pragma unroll
    for (int mb = 0; mb < 4; ++mb)
#pragma unroll
      for (int nb = 0; nb < 2; ++nb)
        acc[mb][nb] = __builtin_amdgcn_mfma_f32_16x16x32_bf16(a[mb], b[nb], acc[mb][nb], 0, 0, 0);
  }
#pragma unroll
  for (int mb = 0; mb < 4; ++mb) {
    int r = row0 + mb * 16 + lk * 4;
#pragma unroll
    for (int nb = 0; nb < 2; ++nb) {
      int c = w * 32 + nb * 16 + lr;
#pragma unroll
      for (int j = 0; j < 4; ++j)
        if (r + j < N) out[(size_t)(r + j) * 128 + c] = f2bf(acc[mb][nb][j]);
    }
  }
}

// fused layer-2: h1 tile computed elementwise into LDS, then h1 @ [W2l;W2r].T
__global__ __launch_bounds__(TPB) void k_lin2(
    const float* __restrict__ agg1, const unsigned short* __restrict__ r1,
    const int* __restrict__ cnt, const float* __restrict__ b1,
    const float* __restrict__ W2l, const float* __restrict__ W2r,
    unsigned short* __restrict__ y2, unsigned short* __restrict__ r2, int N) {
  __shared__ unsigned short Bs[128 * LD];
  __shared__ unsigned short As[64 * LD];
  int t = threadIdx.x;
  for (int i = t; i < 128 * 32; i += TPB) {  // B rows 0-63: W2l, 64-127: W2r
    int r = i >> 5, k4 = i & 31;
    const float* src = (r < 64) ? &W2l[(size_t)r * 128 + k4 * 4]
                                : &W2r[(size_t)(r - 64) * 128 + k4 * 4];
    float4 v = *(const float4*)src;
    ushort4 o; o.x = f2bf(v.x); o.y = f2bf(v.y); o.z = f2bf(v.z); o.w = f2bf(v.w);
    *(ushort4*)&Bs[r * LD + k4 * 4] = o;
  }
  int row0 = blockIdx.x * 64;
  for (int i = t; i < 64 * 32; i += TPB) {  // compute h1 tile -> As
    int r = i >> 5, k4 = i & 31;
    int gr = row0 + r;
    float h0 = 0.f, h1v = 0.f, h2v = 0.f, h3v = 0.f;
    if (gr < N) {
      int d = cnt[gr];
      float inv = 1.f / (float)(d > 1 ? d : 1);
      float4 a = *(const float4*)&agg1[(size_t)gr * 128 + k4 * 4];
      ushort4 rr = *(const ushort4*)&r1[(size_t)gr * 128 + k4 * 4];
      float4 bb = *(const float4*)&b1[k4 * 4];
      h0 = a.x * inv + bf2f(rr.x) + bb.x;
      h1v = a.y * inv + bf2f(rr.y) + bb.y;
      h2v = a.z * inv + bf2f(rr.z) + bb.z;
      h3v = a.w * inv + bf2f(rr.w) + bb.w;
      h0 = h0 > 0.f ? h0 : 0.f; h1v = h1v > 0.f ? h1v : 0.f;
      h2v = h2v > 0.f ? h2v : 0.f; h3v = h3v > 0.f ? h3v : 0.f;
    }
    ushort4 o; o.x = f2bf(h0); o.y = f2bf(h1v); o.z = f2bf(h2v); o.w = f2bf(h3v);
    *(ushort4*)&As[r * LD + k4 * 4] = o;
  }
  __syncthreads();
  int w = t >> 6, l = t & 63;
  int lr = l & 15, lk = l >> 4;
  f32x4 acc[4][2];
#pragma unroll
  for (int mb = 0; mb < 4; ++mb)
#pragma unroll
    for (int nb = 0; nb < 2; ++nb)
#pragma unroll
      for (int q = 0; q < 4; ++q) acc[mb][nb][q] = 0.f;
#pragma unroll
  for (int ks = 0; ks < 4; ++ks) {
    int koff = ks * 32 + lk * 8;
    bf16x8 a[4], b[2];
#pragma unroll
    for (int mb = 0; mb < 4; ++mb)
      a[mb] = *(const bf16x8*)&As[(mb * 16 + lr) * LD + koff];
#pragma unroll
    for (int nb = 0; nb < 2; ++nb)
      b[nb] = *(const bf16x8*)&Bs[(w * 32 + nb * 16 + lr) * LD + koff];
#pragma unroll
    for (int mb = 0; mb < 4; ++mb)
#pragma unroll
      for (int nb = 0; nb < 2; ++nb)
        acc[mb][nb] = __builtin_amdgcn_mfma_f32_16x16x32_bf16(a[mb], b[nb], acc[mb][nb], 0, 0, 0);
  }
#pragma unroll
  for (int mb = 0; mb < 4; ++mb) {
    int r = row0 + mb * 16 + lk * 4;
#pragma unroll
    for (int nb = 0; nb < 2; ++nb) {
      int c = w * 32 + nb * 16 + lr;
#pragma unroll
      for (int j = 0; j < 4; ++j) {
        if (r + j < N) {
          unsigned short val = f2bf(acc[mb][nb][j]);
          if (c < 64) y2[(size_t)(r + j) * 64 + c] = val;
          else        r2[(size_t)(r + j) * 64 + (c - 64)] = val;
        }
      }
    }
  }
}

// ---------------- gather aggregation (bf16 tables, f32 accum) ----------------
__global__ void k_aggb1(const unsigned short* __restrict__ feat, const int* __restrict__ rowptr,
                        const int* __restrict__ col, float* __restrict__ out, int n) {
  int wid = (int)(((size_t)blockIdx.x * blockDim.x + threadIdx.x) >> 6);
  int l = threadIdx.x & 63;
  if (wid >= n) return;
  int rp0 = rowptr[wid], rp1 = rowptr[wid + 1];
  float ax = 0.f, ay = 0.f;
  int j = rp0;
  for (; j + 1 < rp1; j += 2) {
    int c0 = col[j], c1 = col[j + 1];
    ushort2 v0 = *(const ushort2*)&feat[(size_t)c0 * 128 + l * 2];
    ushort2 v1 = *(const ushort2*)&feat[(size_t)c1 * 128 + l * 2];
    ax += bf2f(v0.x) + bf2f(v1.x);
    ay += bf2f(v0.y) + bf2f(v1.y);
  }
  if (j < rp1) {
    int c0 = col[j];
    ushort2 v0 = *(const ushort2*)&feat[(size_t)c0 * 128 + l * 2];
    ax += bf2f(v0.x); ay += bf2f(v0.y);
  }
  float2 o; o.x = ax; o.y = ay;
  *(float2*)&out[(size_t)wid * 128 + l * 2] = o;
}

__global__ void k_aggb2(const unsigned short* __restrict__ feat, const int* __restrict__ rowptr,
                        const int* __restrict__ col, float* __restrict__ out, int n) {
  int wid = (int)(((size_t)blockIdx.x * blockDim.x + threadIdx.x) >> 6);
  int l = threadIdx.x & 63;
  if (wid >= n) return;
  int rp0 = rowptr[wid], rp1 = rowptr[wid + 1];
  int h = l >> 5, ln = l & 31;
  float ax = 0.f, ay = 0.f;
  for (int j = rp0 + h; j < rp1; j += 2) {  // lanes 0-31: even nbrs, 32-63: odd
    int c = col[j];
    ushort2 v = *(const ushort2*)&feat[(size_t)c * 64 + ln * 2];
    ax += bf2f(v.x); ay += bf2f(v.y);
  }
  ax += __shfl_xor(ax, 32, 64);
  ay += __shfl_xor(ay, 32, 64);
  if (h == 0) {
    float2 o; o.x = ax; o.y = ay;
    *(float2*)&out[(size_t)wid * 64 + ln * 2] = o;
  }
}

// ---------------- fused h2 + classifier ----------------
__global__ void k_head(const float* __restrict__ agg2, const unsigned short* __restrict__ r2,
                       const int* __restrict__ cnt, const float* __restrict__ b2,
                       const float* __restrict__ Wc, const float* __restrict__ bc,
                       float* __restrict__ out, int n) {
  int wid = (int)(((size_t)blockIdx.x * blockDim.x + threadIdx.x) >> 6);
  int l = threadIdx.x & 63;
  if (wid >= n) return;
  int d = cnt[wid];
  float inv = 1.f / (float)(d > 1 ? d : 1);
  float h = agg2[(size_t)wid * 64 + l] * inv + bf2f(r2[(size_t)wid * 64 + l]) + b2[l];
  h = h > 0.f ? h : 0.f;
  float v = h * Wc[l];
  for (int off = 32; off; off >>= 1) v += __shfl_down(v, off, 64);
  if (l == 0) out[wid] = v + bc[0];
}

extern "C" void kernel_launch(void* const* d_in, const int* in_sizes, int n_in,
                              void* d_out, int out_size, void* d_ws, size_t ws_size,
                              hipStream_t stream) {
  const float* x   = (const float*)d_in[0];
  const int*   ei  = (const int*)d_in[1];
  const float* W1l = (const float*)d_in[2];
  const float* W1r = (const float*)d_in[3];
  const float* b1  = (const float*)d_in[4];
  const float* W2l = (const float*)d_in[5];
  const float* W2r = (const float*)d_in[6];
  const float* b2  = (const float*)d_in[7];
  const float* Wc  = (const float*)d_in[8];
  const float* bc  = (const float*)d_in[9];
  float* logits = (float*)d_out;

  const int N = in_sizes[0] / 128;  // 100000
  const int E = in_sizes[1] / 2;    // 1600000

  char* ws = (char*)d_ws;
  size_t o = 0;
  auto alloc = [&](size_t bytes) { size_t r = o; o += (bytes + 511) & ~511ULL; return r; };
  size_t o_cnt  = alloc((size_t)N * 4);
  size_t o_rp   = alloc((size_t)(N + 1) * 4);
  size_t o_cur  = alloc((size_t)N * 4);
  size_t o_bs   = alloc(512 * 4);
  size_t o_col  = alloc((size_t)E * 4);
  size_t o_t1   = alloc((size_t)N * 128 * 2);  // bf16; later reused for y2|r2
  size_t o_r1   = alloc((size_t)N * 128 * 2);  // bf16; later reused for agg2 (f32 N*64)
  size_t o_agg1 = alloc((size_t)N * 128 * 4);  // f32
  if (o > ws_size) return;

  int* cnt = (int*)(ws + o_cnt);
  int* rp  = (int*)(ws + o_rp);
  int* cur = (int*)(ws + o_cur);
  int* bs  = (int*)(ws + o_bs);
  int* col = (int*)(ws + o_col);
  unsigned short* t1 = (unsigned short*)(ws + o_t1);
  unsigned short* r1 = (unsigned short*)(ws + o_r1);
  float* agg1 = (float*)(ws + o_agg1);
  // reuse: t1 region (N*128*2 B) holds y2 (N*64 bf16) + r2 (N*64 bf16)
  unsigned short* y2 = t1;
  unsigned short* r2 = t1 + (size_t)N * 64;
  // reuse: r1 region (N*128*2 B) holds agg2 (N*64 f32)
  float* agg2 = (float*)(ws + o_r1);

  const int* esrc = ei;
  const int* edst = ei + E;

  // CSR build
  k_zero<<<(N + TPB - 1) / TPB, TPB, 0, stream>>>(cnt, N);
  int eb = (E + TPB - 1) / TPB;
  k_count<<<eb, TPB, 0, stream>>>(edst, cnt, E);
  int nb = (N + 1023) / 1024;  // 98 <= 128
  k_scan_a<<<nb, TPB, 0, stream>>>(cnt, bs, N);
  k_scan_b<<<1, 128, 0, stream>>>(bs, nb);
  k_scan_c<<<nb, TPB, 0, stream>>>(cnt, bs, rp, cur, N, E);
  k_fill<<<eb, TPB, 0, stream>>>(esrc, edst, cur, col, E);

  int gtiles = (N + 63) / 64;                        // 1563
  int nodeblocks = (int)(((size_t)N * 64 + TPB - 1) / TPB);  // 25000

  k_lin1<<<gtiles, TPB, 0, stream>>>(x, W1l, t1, N);
  k_lin1<<<gtiles, TPB, 0, stream>>>(x, W1r, r1, N);
  k_aggb1<<<nodeblocks, TPB, 0, stream>>>(t1, rp, col, agg1, N);
  k_lin2<<<gtiles, TPB, 0, stream>>>(agg1, r1, cnt, b1, W2l, W2r, y2, r2, N);
  k_aggb2<<<nodeblocks, TPB, 0, stream>>>(y2, rp, col, agg2, N);
  k_head<<<nodeblocks, TPB, 0, stream>>>(agg2, r2, cnt, b2, Wc, bc, logits, N);
}

// Round 3
// 450.244 us; speedup vs baseline: 2.1298x; 1.0658x over previous
//
#include <hip/hip_runtime.h>

// GraphSAGE 2-layer + classifier on MI355X (gfx950).
// bf16 MFMA GEMMs + CSR gather aggregation + XCD-partitioned CSR build.
//
// Pipeline:
//   CSR: cnt (XCD-partitioned count) -> scan -> rowptr/cursor -> fill (XCD-partitioned)
//   t1 = bf16(x @ W1l.T)                    k_lin1(W1l)
//   r1 = bf16(x @ W1r.T)                    k_lin1(W1r)
//   agg1 = gather-sum(t1) f32               k_aggb1
//   h1 = relu(agg1/deg + r1 + b1) [LDS only]
//   y2 = bf16(h1 @ W2l.T), r2 = bf16(h1 @ W2r.T)   k_lin2 (fused)
//   agg2 = gather-sum(y2) f32               k_aggb2
//   logits = (relu(agg2/deg + r2 + b2)) . Wc + bc  k_head (fused)

static constexpr int TPB = 256;

typedef __attribute__((ext_vector_type(8))) short bf16x8;
typedef __attribute__((ext_vector_type(4))) float f32x4;

__device__ __forceinline__ unsigned short f2bf(float f) {
  union { float f; unsigned u; } v; v.f = f;
  unsigned r = v.u + 0x7FFFu + ((v.u >> 16) & 1u);  // RNE
  return (unsigned short)(r >> 16);
}
__device__ __forceinline__ float bf2f(unsigned short h) {
  union { unsigned u; float f; } v; v.u = ((unsigned)h) << 16;
  return v.f;
}

// ---------------- CSR build ----------------
__global__ void k_zero(int* __restrict__ p, int n) {
  int i = blockIdx.x * blockDim.x + threadIdx.x;
  if (i < n) p[i] = 0;
}

// XCD-partitioned count: blocks with blockIdx%8==p count only dst in slice p.
// Each slice's cnt region (~50KB) stays in one XCD's L2 -> local atomics,
// single-writer lines.
__global__ void k_count_part(const int* __restrict__ dst, int* __restrict__ cnt,
                             int E, int psize) {
  int part = blockIdx.x & 7;
  int q = blockIdx.x >> 3;
  int nq = (int)(gridDim.x >> 3);
  int lo = part * psize, hi = lo + psize;
  for (int i = q * blockDim.x + threadIdx.x; i < E; i += nq * blockDim.x) {
    int d = dst[i];
    if (d >= lo && d < hi) atomicAdd(&cnt[d], 1);
  }
}

__global__ void k_scan_a(const int* __restrict__ cnt, int* __restrict__ bsums, int n) {
  __shared__ int s[TPB];
  int t = threadIdx.x;
  int base = blockIdx.x * 1024 + t * 4;
  int v = 0;
#pragma unroll
  for (int j = 0; j < 4; ++j) { int idx = base + j; if (idx < n) v += cnt[idx]; }
  s[t] = v; __syncthreads();
  for (int off = TPB / 2; off > 0; off >>= 1) {
    if (t < off) s[t] += s[t + off];
    __syncthreads();
  }
  if (t == 0) bsums[blockIdx.x] = s[0];
}

__global__ void k_scan_b(int* __restrict__ bsums, int nb) {
  __shared__ int s[128];
  int t = threadIdx.x;
  int v = (t < nb) ? bsums[t] : 0;
  s[t] = v; __syncthreads();
  for (int off = 1; off < 128; off <<= 1) {
    int x = (t >= off) ? s[t - off] : 0;
    __syncthreads();
    s[t] += x;
    __syncthreads();
  }
  if (t < nb) bsums[t] = s[t] - v;  // exclusive
}

__global__ void k_scan_c(const int* __restrict__ cnt, const int* __restrict__ bsums,
                         int* __restrict__ rowptr, int* __restrict__ cursor,
                         int n, int total) {
  __shared__ int s[TPB];
  int t = threadIdx.x;
  int base = blockIdx.x * 1024 + t * 4;
  int loc[4]; int v = 0;
#pragma unroll
  for (int j = 0; j < 4; ++j) { int idx = base + j; loc[j] = (idx < n) ? cnt[idx] : 0; v += loc[j]; }
  s[t] = v; __syncthreads();
  for (int off = 1; off < TPB; off <<= 1) {
    int x = (t >= off) ? s[t - off] : 0;
    __syncthreads();
    s[t] += x;
    __syncthreads();
  }
  int run = bsums[blockIdx.x] + (s[t] - v);
#pragma unroll
  for (int j = 0; j < 4; ++j) {
    int idx = base + j;
    if (idx < n) { rowptr[idx] = run; cursor[idx] = run; run += loc[j]; }
  }
  if (blockIdx.x == 0 && t == 0) rowptr[n] = total;
}

// XCD-partitioned fill: slice p's cursor (50KB) and col segment (~800KB)
// are written only by blocks on (nominally) XCD p -> lines merge in local L2
// instead of one masked 64B HBM writeback per 4B store.
__global__ void k_fill_part(const int* __restrict__ src, const int* __restrict__ dst,
                            int* __restrict__ cursor, int* __restrict__ col,
                            int E, int psize) {
  int part = blockIdx.x & 7;
  int q = blockIdx.x >> 3;
  int nq = (int)(gridDim.x >> 3);
  int lo = part * psize, hi = lo + psize;
  for (int i = q * blockDim.x + threadIdx.x; i < E; i += nq * blockDim.x) {
    int d = dst[i];
    if (d >= lo && d < hi) {
      int p = atomicAdd(&cursor[d], 1);
      col[p] = src[i];
    }
  }
}

// ---------------- bf16 MFMA GEMM: out[r][c] = X[r]·W[c], K=128 ----------------
// BM=64 rows/block, NOUT=128 cols, 4 waves (wave w -> cols [w*32, w*32+32)).
// LDS padded to LD=136 bf16/row -> 2-way bank aliasing only (free).
static constexpr int LD = 136;

__global__ __launch_bounds__(TPB) void k_lin1(
    const float* __restrict__ X, const float* __restrict__ W,
    unsigned short* __restrict__ out, int N) {
  __shared__ unsigned short Bs[128 * LD];
  __shared__ unsigned short As[64 * LD];
  int t = threadIdx.x;
  for (int i = t; i < 128 * 32; i += TPB) {  // stage B (W row-major [c][k])
    int r = i >> 5, k4 = i & 31;
    float4 v = *(const float4*)&W[r * 128 + k4 * 4];
    ushort4 o; o.x = f2bf(v.x); o.y = f2bf(v.y); o.z = f2bf(v.z); o.w = f2bf(v.w);
    *(ushort4*)&Bs[r * LD + k4 * 4] = o;
  }
  int row0 = blockIdx.x * 64;
  for (int i = t; i < 64 * 32; i += TPB) {  // stage A (x rows)
    int r = i >> 5, k4 = i & 31;
    int gr = row0 + r;
    float4 v;
    if (gr < N) v = *(const float4*)&X[(size_t)gr * 128 + k4 * 4];
    else { v.x = v.y = v.z = v.w = 0.f; }
    ushort4 o; o.x = f2bf(v.x); o.y = f2bf(v.y); o.z = f2bf(v.z); o.w = f2bf(v.w);
    *(ushort4*)&As[r * LD + k4 * 4] = o;
  }
  __syncthreads();
  int w = t >> 6, l = t & 63;
  int lr = l & 15, lk = l >> 4;  // lr: row/col-in-frag, lk: k-group
  f32x4 acc[4][2];
#pragma unroll
  for (int mb = 0; mb < 4; ++mb)
#pragma unroll
    for (int nb = 0; nb < 2; ++nb)
#pragma unroll
      for (int q = 0; q < 4; ++q) acc[mb][nb][q] = 0.f;
#pragma unroll
  for (int ks = 0; ks < 4; ++ks) {
    int koff = ks * 32 + lk * 8;
    bf16x8 a[4], b[2];
#pragma unroll
    for (int mb = 0; mb < 4; ++mb)
      a[mb] = *(const bf16x8*)&As[(mb * 16 + lr) * LD + koff];
#pragma unroll
    for (int nb = 0; nb < 2; ++nb)
      b[nb] = *(const bf16x8*)&Bs[(w * 32 + nb * 16 + lr) * LD + koff];
#pragma unroll
    for (int mb = 0; mb < 4; ++mb)
#pragma unroll
      for (int nb = 0; nb < 2; ++nb)
        acc[mb][nb] = __builtin_amdgcn_mfma_f32_16x16x32_bf16(a[mb], b[nb], acc[mb][nb], 0, 0, 0);
  }
#pragma unroll
  for (int mb = 0; mb < 4; ++mb) {
    int r = row0 + mb * 16 + lk * 4;
#pragma unroll
    for (int nb = 0; nb < 2; ++nb) {
      int c = w * 32 + nb * 16 + lr;
#pragma unroll
      for (int j = 0; j < 4; ++j)
        if (r + j < N) out[(size_t)(r + j) * 128 + c] = f2bf(acc[mb][nb][j]);
    }
  }
}

// fused layer-2: h1 tile computed elementwise into LDS, then h1 @ [W2l;W2r].T
__global__ __launch_bounds__(TPB) void k_lin2(
    const float* __restrict__ agg1, const unsigned short* __restrict__ r1,
    const int* __restrict__ cnt, const float* __restrict__ b1,
    const float* __restrict__ W2l, const float* __restrict__ W2r,
    unsigned short* __restrict__ y2, unsigned short* __restrict__ r2, int N) {
  __shared__ unsigned short Bs[128 * LD];
  __shared__ unsigned short As[64 * LD];
  int t = threadIdx.x;
  for (int i = t; i < 128 * 32; i += TPB) {  // B rows 0-63: W2l, 64-127: W2r
    int r = i >> 5, k4 = i & 31;
    const float* src = (r < 64) ? &W2l[(size_t)r * 128 + k4 * 4]
                                : &W2r[(size_t)(r - 64) * 128 + k4 * 4];
    float4 v = *(const float4*)src;
    ushort4 o; o.x = f2bf(v.x); o.y = f2bf(v.y); o.z = f2bf(v.z); o.w = f2bf(v.w);
    *(ushort4*)&Bs[r * LD + k4 * 4] = o;
  }
  int row0 = blockIdx.x * 64;
  for (int i = t; i < 64 * 32; i += TPB) {  // compute h1 tile -> As
    int r = i >> 5, k4 = i & 31;
    int gr = row0 + r;
    float h0 = 0.f, h1v = 0.f, h2v = 0.f, h3v = 0.f;
    if (gr < N) {
      int d = cnt[gr];
      float inv = 1.f / (float)(d > 1 ? d : 1);
      float4 a = *(const float4*)&agg1[(size_t)gr * 128 + k4 * 4];
      ushort4 rr = *(const ushort4*)&r1[(size_t)gr * 128 + k4 * 4];
      float4 bb = *(const float4*)&b1[k4 * 4];
      h0 = a.x * inv + bf2f(rr.x) + bb.x;
      h1v = a.y * inv + bf2f(rr.y) + bb.y;
      h2v = a.z * inv + bf2f(rr.z) + bb.z;
      h3v = a.w * inv + bf2f(rr.w) + bb.w;
      h0 = h0 > 0.f ? h0 : 0.f; h1v = h1v > 0.f ? h1v : 0.f;
      h2v = h2v > 0.f ? h2v : 0.f; h3v = h3v > 0.f ? h3v : 0.f;
    }
    ushort4 o; o.x = f2bf(h0); o.y = f2bf(h1v); o.z = f2bf(h2v); o.w = f2bf(h3v);
    *(ushort4*)&As[r * LD + k4 * 4] = o;
  }
  __syncthreads();
  int w = t >> 6, l = t & 63;
  int lr = l & 15, lk = l >> 4;
  f32x4 acc[4][2];
#pragma unroll
  for (int mb = 0; mb < 4; ++mb)
#pragma unroll
    for (int nb = 0; nb < 2; ++nb)
#pragma unroll
      for (int q = 0; q < 4; ++q) acc[mb][nb][q] = 0.f;
#pragma unroll
  for (int ks = 0; ks < 4; ++ks) {
    int koff = ks * 32 + lk * 8;
    bf16x8 a[4], b[2];
#pragma unroll
    for (int mb = 0; mb < 4; ++mb)
      a[mb] = *(const bf16x8*)&As[(mb * 16 + lr) * LD + koff];
#pragma unroll
    for (int nb = 0; nb < 2; ++nb)
      b[nb] = *(const bf16x8*)&Bs[(w * 32 + nb * 16 + lr) * LD + koff];
#pragma unroll
    for (int mb = 0; mb < 4; ++mb)
#pragma unroll
      for (int nb = 0; nb < 2; ++nb)
        acc[mb][nb] = __builtin_amdgcn_mfma_f32_16x16x32_bf16(a[mb], b[nb], acc[mb][nb], 0, 0, 0);
  }
#pragma unroll
  for (int mb = 0; mb < 4; ++mb) {
    int r = row0 + mb * 16 + lk * 4;
#pragma unroll
    for (int nb = 0; nb < 2; ++nb) {
      int c = w * 32 + nb * 16 + lr;
#pragma unroll
      for (int j = 0; j < 4; ++j) {
        if (r + j < N) {
          unsigned short val = f2bf(acc[mb][nb][j]);
          if (c < 64) y2[(size_t)(r + j) * 64 + c] = val;
          else        r2[(size_t)(r + j) * 64 + (c - 64)] = val;
        }
      }
    }
  }
}

// ---------------- gather aggregation (bf16 tables, f32 accum) ----------------
__global__ void k_aggb1(const unsigned short* __restrict__ feat, const int* __restrict__ rowptr,
                        const int* __restrict__ col, float* __restrict__ out, int n) {
  int wid = (int)(((size_t)blockIdx.x * blockDim.x + threadIdx.x) >> 6);
  int l = threadIdx.x & 63;
  if (wid >= n) return;
  int rp0 = rowptr[wid], rp1 = rowptr[wid + 1];
  float ax = 0.f, ay = 0.f;
  int j = rp0;
  for (; j + 1 < rp1; j += 2) {
    int c0 = col[j], c1 = col[j + 1];
    ushort2 v0 = *(const ushort2*)&feat[(size_t)c0 * 128 + l * 2];
    ushort2 v1 = *(const ushort2*)&feat[(size_t)c1 * 128 + l * 2];
    ax += bf2f(v0.x) + bf2f(v1.x);
    ay += bf2f(v0.y) + bf2f(v1.y);
  }
  if (j < rp1) {
    int c0 = col[j];
    ushort2 v0 = *(const ushort2*)&feat[(size_t)c0 * 128 + l * 2];
    ax += bf2f(v0.x); ay += bf2f(v0.y);
  }
  float2 o; o.x = ax; o.y = ay;
  *(float2*)&out[(size_t)wid * 128 + l * 2] = o;
}

__global__ void k_aggb2(const unsigned short* __restrict__ feat, const int* __restrict__ rowptr,
                        const int* __restrict__ col, float* __restrict__ out, int n) {
  int wid = (int)(((size_t)blockIdx.x * blockDim.x + threadIdx.x) >> 6);
  int l = threadIdx.x & 63;
  if (wid >= n) return;
  int rp0 = rowptr[wid], rp1 = rowptr[wid + 1];
  int h = l >> 5, ln = l & 31;
  float ax = 0.f, ay = 0.f;
  for (int j = rp0 + h; j < rp1; j += 2) {  // lanes 0-31: even nbrs, 32-63: odd
    int c = col[j];
    ushort2 v = *(const ushort2*)&feat[(size_t)c * 64 + ln * 2];
    ax += bf2f(v.x); ay += bf2f(v.y);
  }
  ax += __shfl_xor(ax, 32, 64);
  ay += __shfl_xor(ay, 32, 64);
  if (h == 0) {
    float2 o; o.x = ax; o.y = ay;
    *(float2*)&out[(size_t)wid * 64 + ln * 2] = o;
  }
}

// ---------------- fused h2 + classifier ----------------
__global__ void k_head(const float* __restrict__ agg2, const unsigned short* __restrict__ r2,
                       const int* __restrict__ cnt, const float* __restrict__ b2,
                       const float* __restrict__ Wc, const float* __restrict__ bc,
                       float* __restrict__ out, int n) {
  int wid = (int)(((size_t)blockIdx.x * blockDim.x + threadIdx.x) >> 6);
  int l = threadIdx.x & 63;
  if (wid >= n) return;
  int d = cnt[wid];
  float inv = 1.f / (float)(d > 1 ? d : 1);
  float h = agg2[(size_t)wid * 64 + l] * inv + bf2f(r2[(size_t)wid * 64 + l]) + b2[l];
  h = h > 0.f ? h : 0.f;
  float v = h * Wc[l];
  for (int off = 32; off; off >>= 1) v += __shfl_down(v, off, 64);
  if (l == 0) out[wid] = v + bc[0];
}

extern "C" void kernel_launch(void* const* d_in, const int* in_sizes, int n_in,
                              void* d_out, int out_size, void* d_ws, size_t ws_size,
                              hipStream_t stream) {
  const float* x   = (const float*)d_in[0];
  const int*   ei  = (const int*)d_in[1];
  const float* W1l = (const float*)d_in[2];
  const float* W1r = (const float*)d_in[3];
  const float* b1  = (const float*)d_in[4];
  const float* W2l = (const float*)d_in[5];
  const float* W2r = (const float*)d_in[6];
  const float* b2  = (const float*)d_in[7];
  const float* Wc  = (const float*)d_in[8];
  const float* bc  = (const float*)d_in[9];
  float* logits = (float*)d_out;

  const int N = in_sizes[0] / 128;  // 100000
  const int E = in_sizes[1] / 2;    // 1600000

  char* ws = (char*)d_ws;
  size_t o = 0;
  auto alloc = [&](size_t bytes) { size_t r = o; o += (bytes + 511) & ~511ULL; return r; };
  size_t o_cnt  = alloc((size_t)N * 4);
  size_t o_rp   = alloc((size_t)(N + 1) * 4);
  size_t o_cur  = alloc((size_t)N * 4);
  size_t o_bs   = alloc(512 * 4);
  size_t o_col  = alloc((size_t)E * 4);
  size_t o_t1   = alloc((size_t)N * 128 * 2);  // bf16; later reused for y2|r2
  size_t o_r1   = alloc((size_t)N * 128 * 2);  // bf16; later reused for agg2 (f32 N*64)
  size_t o_agg1 = alloc((size_t)N * 128 * 4);  // f32
  if (o > ws_size) return;

  int* cnt = (int*)(ws + o_cnt);
  int* rp  = (int*)(ws + o_rp);
  int* cur = (int*)(ws + o_cur);
  int* bs  = (int*)(ws + o_bs);
  int* col = (int*)(ws + o_col);
  unsigned short* t1 = (unsigned short*)(ws + o_t1);
  unsigned short* r1 = (unsigned short*)(ws + o_r1);
  float* agg1 = (float*)(ws + o_agg1);
  // reuse: t1 region (N*128*2 B) holds y2 (N*64 bf16) + r2 (N*64 bf16)
  unsigned short* y2 = t1;
  unsigned short* r2 = t1 + (size_t)N * 64;
  // reuse: r1 region (N*128*2 B) holds agg2 (N*64 f32)
  float* agg2 = (float*)(ws + o_r1);

  const int* esrc = ei;
  const int* edst = ei + E;

  const int psize = (N + 7) / 8;  // 12500

  // CSR build (XCD-partitioned count + fill)
  k_zero<<<(N + TPB - 1) / TPB, TPB, 0, stream>>>(cnt, N);
  k_count_part<<<512, TPB, 0, stream>>>(edst, cnt, E, psize);
  int nb = (N + 1023) / 1024;  // 98 <= 128
  k_scan_a<<<nb, TPB, 0, stream>>>(cnt, bs, N);
  k_scan_b<<<1, 128, 0, stream>>>(bs, nb);
  k_scan_c<<<nb, TPB, 0, stream>>>(cnt, bs, rp, cur, N, E);
  k_fill_part<<<512, TPB, 0, stream>>>(esrc, edst, cur, col, E, psize);

  int gtiles = (N + 63) / 64;                        // 1563
  int nodeblocks = (int)(((size_t)N * 64 + TPB - 1) / TPB);  // 25000

  k_lin1<<<gtiles, TPB, 0, stream>>>(x, W1l, t1, N);
  k_lin1<<<gtiles, TPB, 0, stream>>>(x, W1r, r1, N);
  k_aggb1<<<nodeblocks, TPB, 0, stream>>>(t1, rp, col, agg1, N);
  k_lin2<<<gtiles, TPB, 0, stream>>>(agg1, r1, cnt, b1, W2l, W2r, y2, r2, N);
  k_aggb2<<<nodeblocks, TPB, 0, stream>>>(y2, rp, col, agg2, N);
  k_head<<<nodeblocks, TPB, 0, stream>>>(agg2, r2, cnt, b2, Wc, bc, logits, N);
}

// Round 4
// 348.522 us; speedup vs baseline: 2.7514x; 1.2919x over previous
//
#include <hip/hip_runtime.h>

// GraphSAGE 2-layer + classifier on MI355X (gfx950).
// bf16 MFMA GEMMs + CSR gather aggregation (MLP-optimized) + XCD-partitioned CSR build.
//
// Pipeline:
//   CSR: cnt (XCD-partitioned count) -> scan -> rowptr/cursor -> fill (XCD-partitioned)
//   t1 = bf16(x @ W1l.T), r1 = bf16(x @ W1r.T)     k_lin1d (dual, x read once)
//   agg1 = bf16(gather-sum(t1))                    k_aggb1 (4-group split wave)
//   h1 = relu(agg1/deg + r1 + b1) [LDS only]
//   y2 = bf16(h1 @ W2l.T), r2 = bf16(h1 @ W2r.T)   k_lin2 (fused)
//   agg2 = gather-sum(y2) f32                      k_aggb2 (8-group split wave)
//   logits = (relu(agg2/deg + r2 + b2)) . Wc + bc  k_head (fused)

static constexpr int TPB = 256;

typedef __attribute__((ext_vector_type(8))) short bf16x8;
typedef __attribute__((ext_vector_type(4))) float f32x4;

__device__ __forceinline__ unsigned short f2bf(float f) {
  union { float f; unsigned u; } v; v.f = f;
  unsigned r = v.u + 0x7FFFu + ((v.u >> 16) & 1u);  // RNE
  return (unsigned short)(r >> 16);
}
__device__ __forceinline__ float bf2f(unsigned short h) {
  union { unsigned u; float f; } v; v.u = ((unsigned)h) << 16;
  return v.f;
}

// ---------------- CSR build ----------------
__global__ void k_zero(int* __restrict__ p, int n) {
  int i = blockIdx.x * blockDim.x + threadIdx.x;
  if (i < n) p[i] = 0;
}

// XCD-partitioned count: blocks with blockIdx%8==p count only dst in slice p.
__global__ void k_count_part(const int* __restrict__ dst, int* __restrict__ cnt,
                             int E, int psize) {
  int part = blockIdx.x & 7;
  int q = blockIdx.x >> 3;
  int nq = (int)(gridDim.x >> 3);
  int lo = part * psize, hi = lo + psize;
  for (int i = q * blockDim.x + threadIdx.x; i < E; i += nq * blockDim.x) {
    int d = dst[i];
    if (d >= lo && d < hi) atomicAdd(&cnt[d], 1);
  }
}

__global__ void k_scan_a(const int* __restrict__ cnt, int* __restrict__ bsums, int n) {
  __shared__ int s[TPB];
  int t = threadIdx.x;
  int base = blockIdx.x * 1024 + t * 4;
  int v = 0;
#pragma unroll
  for (int j = 0; j < 4; ++j) { int idx = base + j; if (idx < n) v += cnt[idx]; }
  s[t] = v; __syncthreads();
  for (int off = TPB / 2; off > 0; off >>= 1) {
    if (t < off) s[t] += s[t + off];
    __syncthreads();
  }
  if (t == 0) bsums[blockIdx.x] = s[0];
}

__global__ void k_scan_b(int* __restrict__ bsums, int nb) {
  __shared__ int s[128];
  int t = threadIdx.x;
  int v = (t < nb) ? bsums[t] : 0;
  s[t] = v; __syncthreads();
  for (int off = 1; off < 128; off <<= 1) {
    int x = (t >= off) ? s[t - off] : 0;
    __syncthreads();
    s[t] += x;
    __syncthreads();
  }
  if (t < nb) bsums[t] = s[t] - v;  // exclusive
}

__global__ void k_scan_c(const int* __restrict__ cnt, const int* __restrict__ bsums,
                         int* __restrict__ rowptr, int* __restrict__ cursor,
                         int n, int total) {
  __shared__ int s[TPB];
  int t = threadIdx.x;
  int base = blockIdx.x * 1024 + t * 4;
  int loc[4]; int v = 0;
#pragma unroll
  for (int j = 0; j < 4; ++j) { int idx = base + j; loc[j] = (idx < n) ? cnt[idx] : 0; v += loc[j]; }
  s[t] = v; __syncthreads();
  for (int off = 1; off < TPB; off <<= 1) {
    int x = (t >= off) ? s[t - off] : 0;
    __syncthreads();
    s[t] += x;
    __syncthreads();
  }
  int run = bsums[blockIdx.x] + (s[t] - v);
#pragma unroll
  for (int j = 0; j < 4; ++j) {
    int idx = base + j;
    if (idx < n) { rowptr[idx] = run; cursor[idx] = run; run += loc[j]; }
  }
  if (blockIdx.x == 0 && t == 0) rowptr[n] = total;
}

// XCD-partitioned fill: slice p's cursor and col segment written by one XCD.
__global__ void k_fill_part(const int* __restrict__ src, const int* __restrict__ dst,
                            int* __restrict__ cursor, int* __restrict__ col,
                            int E, int psize) {
  int part = blockIdx.x & 7;
  int q = blockIdx.x >> 3;
  int nq = (int)(gridDim.x >> 3);
  int lo = part * psize, hi = lo + psize;
  for (int i = q * blockDim.x + threadIdx.x; i < E; i += nq * blockDim.x) {
    int d = dst[i];
    if (d >= lo && d < hi) {
      int p = atomicAdd(&cursor[d], 1);
      col[p] = src[i];
    }
  }
}

// ---------------- bf16 MFMA GEMM pieces ----------------
// LDS padded to LD=136 bf16/row -> 2-way bank aliasing only (free).
static constexpr int LD = 136;

// compute a 64x128 output tile from As(64xK128) x Bs(128 rows x K128), write bf16
__device__ __forceinline__ void mfma_tile_128(
    const unsigned short* As, const unsigned short* Bs,
    unsigned short* __restrict__ out, int row0, int N, int w, int l) {
  int lr = l & 15, lk = l >> 4;
  f32x4 acc[4][2];
#pragma unroll
  for (int mb = 0; mb < 4; ++mb)
#pragma unroll
    for (int nb = 0; nb < 2; ++nb)
#pragma unroll
      for (int q = 0; q < 4; ++q) acc[mb][nb][q] = 0.f;
#pragma unroll
  for (int ks = 0; ks < 4; ++ks) {
    int koff = ks * 32 + lk * 8;
    bf16x8 a[4], b[2];
#pragma unroll
    for (int mb = 0; mb < 4; ++mb)
      a[mb] = *(const bf16x8*)&As[(mb * 16 + lr) * LD + koff];
#pragma unroll
    for (int nb = 0; nb < 2; ++nb)
      b[nb] = *(const bf16x8*)&Bs[(w * 32 + nb * 16 + lr) * LD + koff];
#pragma unroll
    for (int mb = 0; mb < 4; ++mb)
#pragma unroll
      for (int nb = 0; nb < 2; ++nb)
        acc[mb][nb] = __builtin_amdgcn_mfma_f32_16x16x32_bf16(a[mb], b[nb], acc[mb][nb], 0, 0, 0);
  }
#pragma unroll
  for (int mb = 0; mb < 4; ++mb) {
    int r = row0 + mb * 16 + lk * 4;
#pragma unroll
    for (int nb = 0; nb < 2; ++nb) {
      int c = w * 32 + nb * 16 + lr;
#pragma unroll
      for (int j = 0; j < 4; ++j)
        if (r + j < N) out[(size_t)(r + j) * 128 + c] = f2bf(acc[mb][nb][j]);
    }
  }
}

// dual-output layer-1: stage x once, run W1l then W1r (Bs restaged between phases)
__global__ __launch_bounds__(TPB) void k_lin1d(
    const float* __restrict__ X, const float* __restrict__ W1l,
    const float* __restrict__ W1r, unsigned short* __restrict__ t1,
    unsigned short* __restrict__ r1, int N) {
  __shared__ unsigned short Bs[128 * LD];
  __shared__ unsigned short As[64 * LD];
  int t = threadIdx.x;
  int row0 = blockIdx.x * 64;
  for (int i = t; i < 64 * 32; i += TPB) {  // stage A (x rows)
    int r = i >> 5, k4 = i & 31;
    int gr = row0 + r;
    float4 v;
    if (gr < N) v = *(const float4*)&X[(size_t)gr * 128 + k4 * 4];
    else { v.x = v.y = v.z = v.w = 0.f; }
    ushort4 o; o.x = f2bf(v.x); o.y = f2bf(v.y); o.z = f2bf(v.z); o.w = f2bf(v.w);
    *(ushort4*)&As[r * LD + k4 * 4] = o;
  }
  for (int i = t; i < 128 * 32; i += TPB) {  // stage B = W1l
    int r = i >> 5, k4 = i & 31;
    float4 v = *(const float4*)&W1l[r * 128 + k4 * 4];
    ushort4 o; o.x = f2bf(v.x); o.y = f2bf(v.y); o.z = f2bf(v.z); o.w = f2bf(v.w);
    *(ushort4*)&Bs[r * LD + k4 * 4] = o;
  }
  __syncthreads();
  int w = t >> 6, l = t & 63;
  mfma_tile_128(As, Bs, t1, row0, N, w, l);
  __syncthreads();  // all reads of Bs done before restage
  for (int i = t; i < 128 * 32; i += TPB) {  // stage B = W1r
    int r = i >> 5, k4 = i & 31;
    float4 v = *(const float4*)&W1r[r * 128 + k4 * 4];
    ushort4 o; o.x = f2bf(v.x); o.y = f2bf(v.y); o.z = f2bf(v.z); o.w = f2bf(v.w);
    *(ushort4*)&Bs[r * LD + k4 * 4] = o;
  }
  __syncthreads();
  mfma_tile_128(As, Bs, r1, row0, N, w, l);
}

// fused layer-2: h1 tile computed elementwise into LDS, then h1 @ [W2l;W2r].T
__global__ __launch_bounds__(TPB) void k_lin2(
    const unsigned short* __restrict__ agg1, const unsigned short* __restrict__ r1,
    const int* __restrict__ cnt, const float* __restrict__ b1,
    const float* __restrict__ W2l, const float* __restrict__ W2r,
    unsigned short* __restrict__ y2, unsigned short* __restrict__ r2, int N) {
  __shared__ unsigned short Bs[128 * LD];
  __shared__ unsigned short As[64 * LD];
  int t = threadIdx.x;
  for (int i = t; i < 128 * 32; i += TPB) {  // B rows 0-63: W2l, 64-127: W2r
    int r = i >> 5, k4 = i & 31;
    const float* src = (r < 64) ? &W2l[(size_t)r * 128 + k4 * 4]
                                : &W2r[(size_t)(r - 64) * 128 + k4 * 4];
    float4 v = *(const float4*)src;
    ushort4 o; o.x = f2bf(v.x); o.y = f2bf(v.y); o.z = f2bf(v.z); o.w = f2bf(v.w);
    *(ushort4*)&Bs[r * LD + k4 * 4] = o;
  }
  int row0 = blockIdx.x * 64;
  for (int i = t; i < 64 * 32; i += TPB) {  // compute h1 tile -> As
    int r = i >> 5, k4 = i & 31;
    int gr = row0 + r;
    float h0 = 0.f, h1v = 0.f, h2v = 0.f, h3v = 0.f;
    if (gr < N) {
      int d = cnt[gr];
      float inv = 1.f / (float)(d > 1 ? d : 1);
      ushort4 a = *(const ushort4*)&agg1[(size_t)gr * 128 + k4 * 4];
      ushort4 rr = *(const ushort4*)&r1[(size_t)gr * 128 + k4 * 4];
      float4 bb = *(const float4*)&b1[k4 * 4];
      h0 = bf2f(a.x) * inv + bf2f(rr.x) + bb.x;
      h1v = bf2f(a.y) * inv + bf2f(rr.y) + bb.y;
      h2v = bf2f(a.z) * inv + bf2f(rr.z) + bb.z;
      h3v = bf2f(a.w) * inv + bf2f(rr.w) + bb.w;
      h0 = h0 > 0.f ? h0 : 0.f; h1v = h1v > 0.f ? h1v : 0.f;
      h2v = h2v > 0.f ? h2v : 0.f; h3v = h3v > 0.f ? h3v : 0.f;
    }
    ushort4 o; o.x = f2bf(h0); o.y = f2bf(h1v); o.z = f2bf(h2v); o.w = f2bf(h3v);
    *(ushort4*)&As[r * LD + k4 * 4] = o;
  }
  __syncthreads();
  int w = t >> 6, l = t & 63;
  int lr = l & 15, lk = l >> 4;
  f32x4 acc[4][2];
#pragma unroll
  for (int mb = 0; mb < 4; ++mb)
#pragma unroll
    for (int nb = 0; nb < 2; ++nb)
#pragma unroll
      for (int q = 0; q < 4; ++q) acc[mb][nb][q] = 0.f;
#pragma unroll
  for (int ks = 0; ks < 4; ++ks) {
    int koff = ks * 32 + lk * 8;
    bf16x8 a[4], b[2];
#pragma unroll
    for (int mb = 0; mb < 4; ++mb)
      a[mb] = *(const bf16x8*)&As[(mb * 16 + lr) * LD + koff];
#pragma unroll
    for (int nb = 0; nb < 2; ++nb)
      b[nb] = *(const bf16x8*)&Bs[(w * 32 + nb * 16 + lr) * LD + koff];
#pragma unroll
    for (int mb = 0; mb < 4; ++mb)
#pragma unroll
      for (int nb = 0; nb < 2; ++nb)
        acc[mb][nb] = __builtin_amdgcn_mfma_f32_16x16x32_bf16(a[mb], b[nb], acc[mb][nb], 0, 0, 0);
  }
#pragma unroll
  for (int mb = 0; mb < 4; ++mb) {
    int r = row0 + mb * 16 + lk * 4;
#pragma unroll
    for (int nb = 0; nb < 2; ++nb) {
      int c = w * 32 + nb * 16 + lr;
#pragma unroll
      for (int j = 0; j < 4; ++j) {
        if (r + j < N) {
          unsigned short val = f2bf(acc[mb][nb][j]);
          if (c < 64) y2[(size_t)(r + j) * 64 + c] = val;
          else        r2[(size_t)(r + j) * 64 + (c - 64)] = val;
        }
      }
    }
  }
}

// ---------------- gather aggregation (bf16 tables, f32 accum, split-wave MLP) ----
// layer 1: 128-dim rows. Wave = 1 node; 4 groups x 16 lanes; lane loads bf16x8
// (16B). 2-deep unroll -> 8 feat rows in flight per wave. Output bf16.
__global__ void k_aggb1(const unsigned short* __restrict__ feat, const int* __restrict__ rowptr,
                        const int* __restrict__ col, unsigned short* __restrict__ out, int n) {
  int wid = (int)(((size_t)blockIdx.x * blockDim.x + threadIdx.x) >> 6);
  int l = threadIdx.x & 63;
  if (wid >= n) return;
  int rp0 = rowptr[wid], rp1 = rowptr[wid + 1];
  int g = l >> 4, s = l & 15;
  float acc[8];
#pragma unroll
  for (int q = 0; q < 8; ++q) acc[q] = 0.f;
  int j = rp0 + g;
  for (; j + 4 < rp1; j += 8) {
    int c0 = col[j], c1 = col[j + 4];
    bf16x8 v0 = *(const bf16x8*)&feat[(size_t)c0 * 128 + s * 8];
    bf16x8 v1 = *(const bf16x8*)&feat[(size_t)c1 * 128 + s * 8];
#pragma unroll
    for (int q = 0; q < 8; ++q)
      acc[q] += bf2f((unsigned short)v0[q]) + bf2f((unsigned short)v1[q]);
  }
  if (j < rp1) {
    int c0 = col[j];
    bf16x8 v0 = *(const bf16x8*)&feat[(size_t)c0 * 128 + s * 8];
#pragma unroll
    for (int q = 0; q < 8; ++q) acc[q] += bf2f((unsigned short)v0[q]);
  }
#pragma unroll
  for (int q = 0; q < 8; ++q) {
    acc[q] += __shfl_xor(acc[q], 16, 64);
    acc[q] += __shfl_xor(acc[q], 32, 64);
  }
  if (g == 0) {
    bf16x8 o;
#pragma unroll
    for (int q = 0; q < 8; ++q) o[q] = (short)f2bf(acc[q]);
    *(bf16x8*)&out[(size_t)wid * 128 + s * 8] = o;
  }
}

// layer 2: 64-dim rows. 8 groups x 8 lanes; lane loads bf16x8 (16B).
// 2-deep unroll -> 16 rows in flight. Output f32.
__global__ void k_aggb2(const unsigned short* __restrict__ feat, const int* __restrict__ rowptr,
                        const int* __restrict__ col, float* __restrict__ out, int n) {
  int wid = (int)(((size_t)blockIdx.x * blockDim.x + threadIdx.x) >> 6);
  int l = threadIdx.x & 63;
  if (wid >= n) return;
  int rp0 = rowptr[wid], rp1 = rowptr[wid + 1];
  int g = l >> 3, s = l & 7;
  float acc[8];
#pragma unroll
  for (int q = 0; q < 8; ++q) acc[q] = 0.f;
  int j = rp0 + g;
  for (; j + 8 < rp1; j += 16) {
    int c0 = col[j], c1 = col[j + 8];
    bf16x8 v0 = *(const bf16x8*)&feat[(size_t)c0 * 64 + s * 8];
    bf16x8 v1 = *(const bf16x8*)&feat[(size_t)c1 * 64 + s * 8];
#pragma unroll
    for (int q = 0; q < 8; ++q)
      acc[q] += bf2f((unsigned short)v0[q]) + bf2f((unsigned short)v1[q]);
  }
  if (j < rp1) {
    int c0 = col[j];
    bf16x8 v0 = *(const bf16x8*)&feat[(size_t)c0 * 64 + s * 8];
#pragma unroll
    for (int q = 0; q < 8; ++q) acc[q] += bf2f((unsigned short)v0[q]);
  }
#pragma unroll
  for (int q = 0; q < 8; ++q) {
    acc[q] += __shfl_xor(acc[q], 8, 64);
    acc[q] += __shfl_xor(acc[q], 16, 64);
    acc[q] += __shfl_xor(acc[q], 32, 64);
  }
  if (g == 0) {
    float4 o0, o1;
    o0.x = acc[0]; o0.y = acc[1]; o0.z = acc[2]; o0.w = acc[3];
    o1.x = acc[4]; o1.y = acc[5]; o1.z = acc[6]; o1.w = acc[7];
    *(float4*)&out[(size_t)wid * 64 + s * 8] = o0;
    *(float4*)&out[(size_t)wid * 64 + s * 8 + 4] = o1;
  }
}

// ---------------- fused h2 + classifier ----------------
__global__ void k_head(const float* __restrict__ agg2, const unsigned short* __restrict__ r2,
                       const int* __restrict__ cnt, const float* __restrict__ b2,
                       const float* __restrict__ Wc, const float* __restrict__ bc,
                       float* __restrict__ out, int n) {
  int wid = (int)(((size_t)blockIdx.x * blockDim.x + threadIdx.x) >> 6);
  int l = threadIdx.x & 63;
  if (wid >= n) return;
  int d = cnt[wid];
  float inv = 1.f / (float)(d > 1 ? d : 1);
  float h = agg2[(size_t)wid * 64 + l] * inv + bf2f(r2[(size_t)wid * 64 + l]) + b2[l];
  h = h > 0.f ? h : 0.f;
  float v = h * Wc[l];
  for (int off = 32; off; off >>= 1) v += __shfl_down(v, off, 64);
  if (l == 0) out[wid] = v + bc[0];
}

extern "C" void kernel_launch(void* const* d_in, const int* in_sizes, int n_in,
                              void* d_out, int out_size, void* d_ws, size_t ws_size,
                              hipStream_t stream) {
  const float* x   = (const float*)d_in[0];
  const int*   ei  = (const int*)d_in[1];
  const float* W1l = (const float*)d_in[2];
  const float* W1r = (const float*)d_in[3];
  const float* b1  = (const float*)d_in[4];
  const float* W2l = (const float*)d_in[5];
  const float* W2r = (const float*)d_in[6];
  const float* b2  = (const float*)d_in[7];
  const float* Wc  = (const float*)d_in[8];
  const float* bc  = (const float*)d_in[9];
  float* logits = (float*)d_out;

  const int N = in_sizes[0] / 128;  // 100000
  const int E = in_sizes[1] / 2;    // 1600000

  char* ws = (char*)d_ws;
  size_t o = 0;
  auto alloc = [&](size_t bytes) { size_t r = o; o += (bytes + 511) & ~511ULL; return r; };
  size_t o_cnt  = alloc((size_t)N * 4);
  size_t o_rp   = alloc((size_t)(N + 1) * 4);
  size_t o_cur  = alloc((size_t)N * 4);
  size_t o_bs   = alloc(512 * 4);
  size_t o_col  = alloc((size_t)E * 4);
  size_t o_t1   = alloc((size_t)N * 128 * 2);  // bf16 t1; later reused for y2|r2
  size_t o_r1   = alloc((size_t)N * 128 * 2);  // bf16 r1; later reused for agg2 (f32 N*64)
  size_t o_agg1 = alloc((size_t)N * 128 * 2);  // bf16 agg1
  if (o > ws_size) return;

  int* cnt = (int*)(ws + o_cnt);
  int* rp  = (int*)(ws + o_rp);
  int* cur = (int*)(ws + o_cur);
  int* bs  = (int*)(ws + o_bs);
  int* col = (int*)(ws + o_col);
  unsigned short* t1 = (unsigned short*)(ws + o_t1);
  unsigned short* r1 = (unsigned short*)(ws + o_r1);
  unsigned short* agg1 = (unsigned short*)(ws + o_agg1);
  // reuse: t1 region holds y2 (N*64 bf16) + r2 (N*64 bf16) after aggb1
  unsigned short* y2 = t1;
  unsigned short* r2 = t1 + (size_t)N * 64;
  // reuse: r1 region holds agg2 (N*64 f32) after lin2 consumed r1
  float* agg2 = (float*)(ws + o_r1);

  const int* esrc = ei;
  const int* edst = ei + E;

  const int psize = (N + 7) / 8;  // 12500

  // CSR build (XCD-partitioned count + fill)
  k_zero<<<(N + TPB - 1) / TPB, TPB, 0, stream>>>(cnt, N);
  k_count_part<<<512, TPB, 0, stream>>>(edst, cnt, E, psize);
  int nb = (N + 1023) / 1024;  // 98 <= 128
  k_scan_a<<<nb, TPB, 0, stream>>>(cnt, bs, N);
  k_scan_b<<<1, 128, 0, stream>>>(bs, nb);
  k_scan_c<<<nb, TPB, 0, stream>>>(cnt, bs, rp, cur, N, E);
  k_fill_part<<<512, TPB, 0, stream>>>(esrc, edst, cur, col, E, psize);

  int gtiles = (N + 63) / 64;                        // 1563
  int nodeblocks = (int)(((size_t)N * 64 + TPB - 1) / TPB);  // 25000

  k_lin1d<<<gtiles, TPB, 0, stream>>>(x, W1l, W1r, t1, r1, N);
  k_aggb1<<<nodeblocks, TPB, 0, stream>>>(t1, rp, col, agg1, N);
  k_lin2<<<gtiles, TPB, 0, stream>>>(agg1, r1, cnt, b1, W2l, W2r, y2, r2, N);
  k_aggb2<<<nodeblocks, TPB, 0, stream>>>(y2, rp, col, agg2, N);
  k_head<<<nodeblocks, TPB, 0, stream>>>(agg2, r2, cnt, b2, Wc, bc, logits, N);
}

// Round 5
// 245.762 us; speedup vs baseline: 3.9018x; 1.4181x over previous
//
#include <hip/hip_runtime.h>

// GraphSAGE 2-layer + classifier on MI355X (gfx950).
// bf16 MFMA GEMMs + CSR gather aggregation + atomic-free bucket CSR build.
//
// CSR build (no per-edge global atomics):
//   k_bcount:   LDS histogram over 391 buckets (dst>>8), flush via 391 atomics/WG
//   k_bscan:    1-WG scan of bucket counts -> bbase/bcur
//   k_bscatter: stage edge chunk in LDS, reserve per-bucket runs, write (src,dst)
//               pairs grouped by bucket (sequential-ish 64B runs)
//   k_bcsr:     1 WG per bucket: LDS degree count + scan -> rowptr, col scatter
//               (writes confined to a 16KB window per WG)
// Dense/gather pipeline:
//   t1 = bf16(x @ W1l.T), r1 = bf16(x @ W1r.T)     k_lin1d (x staged once)
//   agg1 = bf16(gather-sum(t1))                    k_aggb1 (4x16 split wave)
//   y2,r2 = bf16(relu(agg1/deg+r1+b1) @ [W2l;W2r]) k_lin2  (deg from rowptr)
//   agg2 = gather-sum(y2) f32                      k_aggb2 (8x8 split wave)
//   logits = relu(agg2/deg+r2+b2) . Wc + bc        k_head

static constexpr int TPB = 256;
static constexpr int NWG = 512;   // edge-chunk workgroups

typedef __attribute__((ext_vector_type(8))) short bf16x8;
typedef __attribute__((ext_vector_type(4))) float f32x4;

__device__ __forceinline__ unsigned short f2bf(float f) {
  union { float f; unsigned u; } v; v.f = f;
  unsigned r = v.u + 0x7FFFu + ((v.u >> 16) & 1u);  // RNE
  return (unsigned short)(r >> 16);
}
__device__ __forceinline__ float bf2f(unsigned short h) {
  union { unsigned u; float f; } v; v.u = ((unsigned)h) << 16;
  return v.f;
}

// ---------------- bucket CSR build ----------------
__global__ void k_zero(int* __restrict__ p, int n) {
  int i = blockIdx.x * blockDim.x + threadIdx.x;
  if (i < n) p[i] = 0;
}

// per-WG LDS histogram of dst>>8, flushed with one global atomic per bucket
__global__ __launch_bounds__(TPB) void k_bcount(const int* __restrict__ dst,
                                                int* __restrict__ bcnt,
                                                int E, int NB, int EC) {
  extern __shared__ int lhist[];  // NB ints
  int t = threadIdx.x;
  for (int b = t; b < NB; b += TPB) lhist[b] = 0;
  __syncthreads();
  int base = blockIdx.x * EC;
  int cnt = min(EC, E - base);
  for (int i = t; i < cnt; i += TPB)
    atomicAdd(&lhist[dst[base + i] >> 8], 1);
  __syncthreads();
  for (int b = t; b < NB; b += TPB) {
    int c = lhist[b];
    if (c) atomicAdd(&bcnt[b], c);
  }
}

// single-WG exclusive scan of bucket counts
__global__ void k_bscan(const int* __restrict__ bcnt, int* __restrict__ bbase,
                        int* __restrict__ bcur, int NB) {
  __shared__ int s[512];
  int t = threadIdx.x;
  int v = (t < NB) ? bcnt[t] : 0;
  s[t] = v; __syncthreads();
  for (int off = 1; off < 512; off <<= 1) {
    int x = (t >= off) ? s[t - off] : 0;
    __syncthreads();
    s[t] += x;
    __syncthreads();
  }
  if (t < NB) {
    int e = s[t] - v;
    bbase[t] = e; bcur[t] = e;
  }
  if (t == NB - 1) bbase[NB] = s[t];
}

// stage edge chunk in LDS, reserve bucket runs, emit (src,dst) grouped by bucket
__global__ __launch_bounds__(TPB) void k_bscatter(const int* __restrict__ src,
                                                  const int* __restrict__ dst,
                                                  int* __restrict__ bcur,
                                                  int2* __restrict__ ebuf,
                                                  int E, int NB, int EC) {
  extern __shared__ int smem[];
  int* es = smem;            // EC
  int* ed = smem + EC;       // EC
  int* lhist = ed + EC;      // NB
  int* lcur  = lhist + NB;   // NB
  int t = threadIdx.x;
  for (int b = t; b < NB; b += TPB) lhist[b] = 0;
  int base = blockIdx.x * EC;
  int cnt = min(EC, E - base);
  __syncthreads();
  for (int i = t; i < cnt; i += TPB) {
    int sv = src[base + i], dv = dst[base + i];
    es[i] = sv; ed[i] = dv;
    atomicAdd(&lhist[dv >> 8], 1);
  }
  __syncthreads();
  for (int b = t; b < NB; b += TPB) {
    int c = lhist[b];
    lcur[b] = c ? atomicAdd(&bcur[b], c) : 0;
  }
  __syncthreads();
  for (int i = t; i < cnt; i += TPB) {
    int b = ed[i] >> 8;
    int pos = atomicAdd(&lcur[b], 1);
    int2 p; p.x = es[i]; p.y = ed[i];
    ebuf[pos] = p;
  }
}

// one WG per bucket: degree-count (LDS), scan, rowptr + col scatter
__global__ __launch_bounds__(TPB) void k_bcsr(const int2* __restrict__ ebuf,
                                              const int* __restrict__ bbase,
                                              int* __restrict__ rowptr,
                                              int* __restrict__ col,
                                              int N, int NB) {
  __shared__ int deg[256], sscan[256], lcur[256];
  int b = blockIdx.x;
  int t = threadIdx.x;
  int e0 = bbase[b], e1 = bbase[b + 1];
  int node0 = b << 8;
  deg[t] = 0;
  __syncthreads();
  for (int i = e0 + t; i < e1; i += TPB)
    atomicAdd(&deg[ebuf[i].y & 255], 1);
  __syncthreads();
  int v = deg[t];
  sscan[t] = v; __syncthreads();
  for (int off = 1; off < 256; off <<= 1) {
    int x = (t >= off) ? sscan[t - off] : 0;
    __syncthreads();
    sscan[t] += x;
    __syncthreads();
  }
  int excl = sscan[t] - v;
  if (node0 + t < N) rowptr[node0 + t] = e0 + excl;
  if (b == NB - 1 && t == 0) rowptr[N] = e1;
  lcur[t] = e0 + excl;
  __syncthreads();
  for (int i = e0 + t; i < e1; i += TPB) {
    int2 p = ebuf[i];
    int pos = atomicAdd(&lcur[p.y & 255], 1);
    col[pos] = p.x;
  }
}

// ---------------- bf16 MFMA GEMM pieces ----------------
static constexpr int LD = 136;  // padded bf16 leading dim (2-way aliasing = free)

__device__ __forceinline__ void mfma_tile_128(
    const unsigned short* As, const unsigned short* Bs,
    unsigned short* __restrict__ out, int row0, int N, int w, int l) {
  int lr = l & 15, lk = l >> 4;
  f32x4 acc[4][2];
#pragma unroll
  for (int mb = 0; mb < 4; ++mb)
#pragma unroll
    for (int nb = 0; nb < 2; ++nb)
#pragma unroll
      for (int q = 0; q < 4; ++q) acc[mb][nb][q] = 0.f;
#pragma unroll
  for (int ks = 0; ks < 4; ++ks) {
    int koff = ks * 32 + lk * 8;
    bf16x8 a[4], bfr[2];
#pragma unroll
    for (int mb = 0; mb < 4; ++mb)
      a[mb] = *(const bf16x8*)&As[(mb * 16 + lr) * LD + koff];
#pragma unroll
    for (int nb = 0; nb < 2; ++nb)
      bfr[nb] = *(const bf16x8*)&Bs[(w * 32 + nb * 16 + lr) * LD + koff];
#pragma unroll
    for (int mb = 0; mb < 4; ++mb)
#pragma unroll
      for (int nb = 0; nb < 2; ++nb)
        acc[mb][nb] = __builtin_amdgcn_mfma_f32_16x16x32_bf16(a[mb], bfr[nb], acc[mb][nb], 0, 0, 0);
  }
#pragma unroll
  for (int mb = 0; mb < 4; ++mb) {
    int r = row0 + mb * 16 + lk * 4;
#pragma unroll
    for (int nb = 0; nb < 2; ++nb) {
      int c = w * 32 + nb * 16 + lr;
#pragma unroll
      for (int j = 0; j < 4; ++j)
        if (r + j < N) out[(size_t)(r + j) * 128 + c] = f2bf(acc[mb][nb][j]);
    }
  }
}

// dual-output layer-1: stage x once, run W1l then W1r
__global__ __launch_bounds__(TPB) void k_lin1d(
    const float* __restrict__ X, const float* __restrict__ W1l,
    const float* __restrict__ W1r, unsigned short* __restrict__ t1,
    unsigned short* __restrict__ r1, int N) {
  __shared__ unsigned short Bs[128 * LD];
  __shared__ unsigned short As[64 * LD];
  int t = threadIdx.x;
  int row0 = blockIdx.x * 64;
  for (int i = t; i < 64 * 32; i += TPB) {
    int r = i >> 5, k4 = i & 31;
    int gr = row0 + r;
    float4 v;
    if (gr < N) v = *(const float4*)&X[(size_t)gr * 128 + k4 * 4];
    else { v.x = v.y = v.z = v.w = 0.f; }
    ushort4 o; o.x = f2bf(v.x); o.y = f2bf(v.y); o.z = f2bf(v.z); o.w = f2bf(v.w);
    *(ushort4*)&As[r * LD + k4 * 4] = o;
  }
  for (int i = t; i < 128 * 32; i += TPB) {
    int r = i >> 5, k4 = i & 31;
    float4 v = *(const float4*)&W1l[r * 128 + k4 * 4];
    ushort4 o; o.x = f2bf(v.x); o.y = f2bf(v.y); o.z = f2bf(v.z); o.w = f2bf(v.w);
    *(ushort4*)&Bs[r * LD + k4 * 4] = o;
  }
  __syncthreads();
  int w = t >> 6, l = t & 63;
  mfma_tile_128(As, Bs, t1, row0, N, w, l);
  __syncthreads();
  for (int i = t; i < 128 * 32; i += TPB) {
    int r = i >> 5, k4 = i & 31;
    float4 v = *(const float4*)&W1r[r * 128 + k4 * 4];
    ushort4 o; o.x = f2bf(v.x); o.y = f2bf(v.y); o.z = f2bf(v.z); o.w = f2bf(v.w);
    *(ushort4*)&Bs[r * LD + k4 * 4] = o;
  }
  __syncthreads();
  mfma_tile_128(As, Bs, r1, row0, N, w, l);
}

// fused layer-2: h1 = relu(agg1/deg + r1 + b1) built in LDS, then @ [W2l;W2r].T
__global__ __launch_bounds__(TPB) void k_lin2(
    const unsigned short* __restrict__ agg1, const unsigned short* __restrict__ r1,
    const int* __restrict__ rowptr, const float* __restrict__ b1,
    const float* __restrict__ W2l, const float* __restrict__ W2r,
    unsigned short* __restrict__ y2, unsigned short* __restrict__ r2, int N) {
  __shared__ unsigned short Bs[128 * LD];
  __shared__ unsigned short As[64 * LD];
  int t = threadIdx.x;
  for (int i = t; i < 128 * 32; i += TPB) {
    int r = i >> 5, k4 = i & 31;
    const float* src = (r < 64) ? &W2l[(size_t)r * 128 + k4 * 4]
                                : &W2r[(size_t)(r - 64) * 128 + k4 * 4];
    float4 v = *(const float4*)src;
    ushort4 o; o.x = f2bf(v.x); o.y = f2bf(v.y); o.z = f2bf(v.z); o.w = f2bf(v.w);
    *(ushort4*)&Bs[r * LD + k4 * 4] = o;
  }
  int row0 = blockIdx.x * 64;
  for (int i = t; i < 64 * 32; i += TPB) {
    int r = i >> 5, k4 = i & 31;
    int gr = row0 + r;
    float h0 = 0.f, h1v = 0.f, h2v = 0.f, h3v = 0.f;
    if (gr < N) {
      int d = rowptr[gr + 1] - rowptr[gr];
      float inv = 1.f / (float)(d > 1 ? d : 1);
      ushort4 a = *(const ushort4*)&agg1[(size_t)gr * 128 + k4 * 4];
      ushort4 rr = *(const ushort4*)&r1[(size_t)gr * 128 + k4 * 4];
      float4 bb = *(const float4*)&b1[k4 * 4];
      h0 = bf2f(a.x) * inv + bf2f(rr.x) + bb.x;
      h1v = bf2f(a.y) * inv + bf2f(rr.y) + bb.y;
      h2v = bf2f(a.z) * inv + bf2f(rr.z) + bb.z;
      h3v = bf2f(a.w) * inv + bf2f(rr.w) + bb.w;
      h0 = h0 > 0.f ? h0 : 0.f; h1v = h1v > 0.f ? h1v : 0.f;
      h2v = h2v > 0.f ? h2v : 0.f; h3v = h3v > 0.f ? h3v : 0.f;
    }
    ushort4 o; o.x = f2bf(h0); o.y = f2bf(h1v); o.z = f2bf(h2v); o.w = f2bf(h3v);
    *(ushort4*)&As[r * LD + k4 * 4] = o;
  }
  __syncthreads();
  int w = t >> 6, l = t & 63;
  int lr = l & 15, lk = l >> 4;
  f32x4 acc[4][2];
#pragma unroll
  for (int mb = 0; mb < 4; ++mb)
#pragma unroll
    for (int nb = 0; nb < 2; ++nb)
#pragma unroll
      for (int q = 0; q < 4; ++q) acc[mb][nb][q] = 0.f;
#pragma unroll
  for (int ks = 0; ks < 4; ++ks) {
    int koff = ks * 32 + lk * 8;
    bf16x8 a[4], bfr[2];
#pragma unroll
    for (int mb = 0; mb < 4; ++mb)
      a[mb] = *(const bf16x8*)&As[(mb * 16 + lr) * LD + koff];
#pragma unroll
    for (int nb = 0; nb < 2; ++nb)
      bfr[nb] = *(const bf16x8*)&Bs[(w * 32 + nb * 16 + lr) * LD + koff];
#pragma unroll
    for (int mb = 0; mb < 4; ++mb)
#pragma unroll
      for (int nb = 0; nb < 2; ++nb)
        acc[mb][nb] = __builtin_amdgcn_mfma_f32_16x16x32_bf16(a[mb], bfr[nb], acc[mb][nb], 0, 0, 0);
  }
#pragma unroll
  for (int mb = 0; mb < 4; ++mb) {
    int r = row0 + mb * 16 + lk * 4;
#pragma unroll
    for (int nb = 0; nb < 2; ++nb) {
      int c = w * 32 + nb * 16 + lr;
#pragma unroll
      for (int j = 0; j < 4; ++j) {
        if (r + j < N) {
          unsigned short val = f2bf(acc[mb][nb][j]);
          if (c < 64) y2[(size_t)(r + j) * 64 + c] = val;
          else        r2[(size_t)(r + j) * 64 + (c - 64)] = val;
        }
      }
    }
  }
}

// ---------------- gather aggregation (bf16 tables, f32 accum, split-wave) ----
__global__ void k_aggb1(const unsigned short* __restrict__ feat, const int* __restrict__ rowptr,
                        const int* __restrict__ col, unsigned short* __restrict__ out, int n) {
  int wid = (int)(((size_t)blockIdx.x * blockDim.x + threadIdx.x) >> 6);
  int l = threadIdx.x & 63;
  if (wid >= n) return;
  int rp0 = rowptr[wid], rp1 = rowptr[wid + 1];
  int g = l >> 4, s = l & 15;
  float acc[8];
#pragma unroll
  for (int q = 0; q < 8; ++q) acc[q] = 0.f;
  int j = rp0 + g;
  for (; j + 4 < rp1; j += 8) {
    int c0 = col[j], c1 = col[j + 4];
    bf16x8 v0 = *(const bf16x8*)&feat[(size_t)c0 * 128 + s * 8];
    bf16x8 v1 = *(const bf16x8*)&feat[(size_t)c1 * 128 + s * 8];
#pragma unroll
    for (int q = 0; q < 8; ++q)
      acc[q] += bf2f((unsigned short)v0[q]) + bf2f((unsigned short)v1[q]);
  }
  if (j < rp1) {
    int c0 = col[j];
    bf16x8 v0 = *(const bf16x8*)&feat[(size_t)c0 * 128 + s * 8];
#pragma unroll
    for (int q = 0; q < 8; ++q) acc[q] += bf2f((unsigned short)v0[q]);
  }
#pragma unroll
  for (int q = 0; q < 8; ++q) {
    acc[q] += __shfl_xor(acc[q], 16, 64);
    acc[q] += __shfl_xor(acc[q], 32, 64);
  }
  if (g == 0) {
    bf16x8 o;
#pragma unroll
    for (int q = 0; q < 8; ++q) o[q] = (short)f2bf(acc[q]);
    *(bf16x8*)&out[(size_t)wid * 128 + s * 8] = o;
  }
}

__global__ void k_aggb2(const unsigned short* __restrict__ feat, const int* __restrict__ rowptr,
                        const int* __restrict__ col, float* __restrict__ out, int n) {
  int wid = (int)(((size_t)blockIdx.x * blockDim.x + threadIdx.x) >> 6);
  int l = threadIdx.x & 63;
  if (wid >= n) return;
  int rp0 = rowptr[wid], rp1 = rowptr[wid + 1];
  int g = l >> 3, s = l & 7;
  float acc[8];
#pragma unroll
  for (int q = 0; q < 8; ++q) acc[q] = 0.f;
  int j = rp0 + g;
  for (; j + 8 < rp1; j += 16) {
    int c0 = col[j], c1 = col[j + 8];
    bf16x8 v0 = *(const bf16x8*)&feat[(size_t)c0 * 64 + s * 8];
    bf16x8 v1 = *(const bf16x8*)&feat[(size_t)c1 * 64 + s * 8];
#pragma unroll
    for (int q = 0; q < 8; ++q)
      acc[q] += bf2f((unsigned short)v0[q]) + bf2f((unsigned short)v1[q]);
  }
  if (j < rp1) {
    int c0 = col[j];
    bf16x8 v0 = *(const bf16x8*)&feat[(size_t)c0 * 64 + s * 8];
#pragma unroll
    for (int q = 0; q < 8; ++q) acc[q] += bf2f((unsigned short)v0[q]);
  }
#pragma unroll
  for (int q = 0; q < 8; ++q) {
    acc[q] += __shfl_xor(acc[q], 8, 64);
    acc[q] += __shfl_xor(acc[q], 16, 64);
    acc[q] += __shfl_xor(acc[q], 32, 64);
  }
  if (g == 0) {
    float4 o0, o1;
    o0.x = acc[0]; o0.y = acc[1]; o0.z = acc[2]; o0.w = acc[3];
    o1.x = acc[4]; o1.y = acc[5]; o1.z = acc[6]; o1.w = acc[7];
    *(float4*)&out[(size_t)wid * 64 + s * 8] = o0;
    *(float4*)&out[(size_t)wid * 64 + s * 8 + 4] = o1;
  }
}

// ---------------- fused h2 + classifier ----------------
__global__ void k_head(const float* __restrict__ agg2, const unsigned short* __restrict__ r2,
                       const int* __restrict__ rowptr, const float* __restrict__ b2,
                       const float* __restrict__ Wc, const float* __restrict__ bc,
                       float* __restrict__ out, int n) {
  int wid = (int)(((size_t)blockIdx.x * blockDim.x + threadIdx.x) >> 6);
  int l = threadIdx.x & 63;
  if (wid >= n) return;
  int d = rowptr[wid + 1] - rowptr[wid];
  float inv = 1.f / (float)(d > 1 ? d : 1);
  float h = agg2[(size_t)wid * 64 + l] * inv + bf2f(r2[(size_t)wid * 64 + l]) + b2[l];
  h = h > 0.f ? h : 0.f;
  float v = h * Wc[l];
  for (int off = 32; off; off >>= 1) v += __shfl_down(v, off, 64);
  if (l == 0) out[wid] = v + bc[0];
}

extern "C" void kernel_launch(void* const* d_in, const int* in_sizes, int n_in,
                              void* d_out, int out_size, void* d_ws, size_t ws_size,
                              hipStream_t stream) {
  const float* x   = (const float*)d_in[0];
  const int*   ei  = (const int*)d_in[1];
  const float* W1l = (const float*)d_in[2];
  const float* W1r = (const float*)d_in[3];
  const float* b1  = (const float*)d_in[4];
  const float* W2l = (const float*)d_in[5];
  const float* W2r = (const float*)d_in[6];
  const float* b2  = (const float*)d_in[7];
  const float* Wc  = (const float*)d_in[8];
  const float* bc  = (const float*)d_in[9];
  float* logits = (float*)d_out;

  const int N = in_sizes[0] / 128;  // 100000
  const int E = in_sizes[1] / 2;    // 1600000
  const int NB = (N + 255) >> 8;    // 391 buckets
  const int EC = (E + NWG - 1) / NWG;  // 3125 edges per scatter WG

  char* ws = (char*)d_ws;
  size_t o = 0;
  auto alloc = [&](size_t bytes) { size_t r = o; o += (bytes + 511) & ~511ULL; return r; };
  size_t o_rp    = alloc((size_t)(N + 1) * 4);
  size_t o_bcnt  = alloc((size_t)NB * 4);
  size_t o_bbase = alloc((size_t)(NB + 1) * 4);
  size_t o_bcur  = alloc((size_t)NB * 4);
  size_t o_col   = alloc((size_t)E * 4);
  size_t o_ebuf  = alloc((size_t)E * 8);       // int2 pairs
  size_t o_t1    = alloc((size_t)N * 128 * 2); // bf16 t1; reused for y2|r2
  size_t o_r1    = alloc((size_t)N * 128 * 2); // bf16 r1; reused for agg2 (f32 N*64)
  size_t o_agg1  = alloc((size_t)N * 128 * 2); // bf16 agg1
  if (o > ws_size) return;

  int* rp    = (int*)(ws + o_rp);
  int* bcnt  = (int*)(ws + o_bcnt);
  int* bbase = (int*)(ws + o_bbase);
  int* bcur  = (int*)(ws + o_bcur);
  int* col   = (int*)(ws + o_col);
  int2* ebuf = (int2*)(ws + o_ebuf);
  unsigned short* t1 = (unsigned short*)(ws + o_t1);
  unsigned short* r1 = (unsigned short*)(ws + o_r1);
  unsigned short* agg1 = (unsigned short*)(ws + o_agg1);
  unsigned short* y2 = t1;
  unsigned short* r2 = t1 + (size_t)N * 64;
  float* agg2 = (float*)(ws + o_r1);

  const int* esrc = ei;
  const int* edst = ei + E;

  // CSR build (atomic-light bucket sort)
  k_zero<<<(NB + TPB - 1) / TPB, TPB, 0, stream>>>(bcnt, NB);
  k_bcount<<<NWG, TPB, (size_t)NB * 4, stream>>>(edst, bcnt, E, NB, EC);
  k_bscan<<<1, 512, 0, stream>>>(bcnt, bbase, bcur, NB);
  size_t scat_lds = (size_t)(2 * EC + 2 * NB) * 4;  // ~28KB
  k_bscatter<<<NWG, TPB, scat_lds, stream>>>(esrc, edst, bcur, ebuf, E, NB, EC);
  k_bcsr<<<NB, TPB, 0, stream>>>(ebuf, bbase, rp, col, N, NB);

  int gtiles = (N + 63) / 64;                               // 1563
  int nodeblocks = (int)(((size_t)N * 64 + TPB - 1) / TPB); // 25000

  k_lin1d<<<gtiles, TPB, 0, stream>>>(x, W1l, W1r, t1, r1, N);
  k_aggb1<<<nodeblocks, TPB, 0, stream>>>(t1, rp, col, agg1, N);
  k_lin2<<<gtiles, TPB, 0, stream>>>(agg1, r1, rp, b1, W2l, W2r, y2, r2, N);
  k_aggb2<<<nodeblocks, TPB, 0, stream>>>(y2, rp, col, agg2, N);
  k_head<<<nodeblocks, TPB, 0, stream>>>(agg2, r2, rp, b2, Wc, bc, logits, N);
}